// Round 6
// baseline (2047.450 us; speedup 1.0000x reference)
//
#include <hip/hip_runtime.h>
#include <math.h>

#define HID 128

typedef __attribute__((ext_vector_type(8))) short bf16x8;
typedef __attribute__((ext_vector_type(16))) float f32x16;
typedef unsigned short us;

__device__ __forceinline__ float silu_f(float v) {
    return v / (1.0f + __expf(-v));
}
__device__ __forceinline__ float sigmoid_f(float v) {
    return 1.0f / (1.0f + __expf(-v));
}
__device__ __forceinline__ us bf16hi(float f) {
    return (us)(__float_as_uint(f) >> 16);
}
__device__ __forceinline__ float bf16tof(us u) {
    return __uint_as_float(((unsigned int)u) << 16);
}
__device__ __forceinline__ f32x16 mfma3(bf16x8 ah, bf16x8 al, bf16x8 bh, bf16x8 bl, f32x16 c) {
    c = __builtin_amdgcn_mfma_f32_32x32x16_bf16(ah, bh, c, 0, 0, 0);
    c = __builtin_amdgcn_mfma_f32_32x32x16_bf16(al, bh, c, 0, 0, 0);
    c = __builtin_amdgcn_mfma_f32_32x32x16_bf16(ah, bl, c, 0, 0, 0);
    return c;
}
__device__ __forceinline__ f32x16 mfma2(bf16x8 ah, bf16x8 al, bf16x8 bh, f32x16 c) {
    c = __builtin_amdgcn_mfma_f32_32x32x16_bf16(ah, bh, c, 0, 0, 0);
    c = __builtin_amdgcn_mfma_f32_32x32x16_bf16(al, bh, c, 0, 0, 0);
    return c;
}
__device__ __forceinline__ void split8(const float* v, bf16x8& bh, bf16x8& bl) {
#pragma unroll
    for (int i = 0; i < 8; ++i) {
        us h = bf16hi(v[i]);
        bh[i] = (short)h;
        bl[i] = (short)bf16hi(v[i] - bf16tof(h));
    }
}

// ---------- CSR sort-by-row ----------
__global__ void k_cnt(const int* __restrict__ rows, int* __restrict__ cnti, int E) {
    int i = blockIdx.x * 256 + threadIdx.x;
    if (i < E) atomicAdd(&cnti[rows[i]], 1);
}

__global__ void k_scan(const int* __restrict__ cnti, int* __restrict__ base, int N) {
    __shared__ int part[256];
    int t = threadIdx.x;
    int chunk = (N + 255) / 256;
    int lo = t * chunk, hi = lo + chunk < N ? lo + chunk : N;
    int s = 0;
    for (int i = lo; i < hi; ++i) s += cnti[i];
    part[t] = s;
    __syncthreads();
    for (int off = 1; off < 256; off <<= 1) {
        int v = (t >= off) ? part[t - off] : 0;
        __syncthreads();
        part[t] += v;
        __syncthreads();
    }
    int run = (t == 0) ? 0 : part[t - 1];
    for (int i = lo; i < hi; ++i) { base[i] = run; run += cnti[i]; }
}

__global__ void k_scatter(const int* __restrict__ rows, const int* __restrict__ cols,
                          const float* __restrict__ eattr,
                          const int* __restrict__ base, int* __restrict__ fill,
                          int* __restrict__ srow, int* __restrict__ scol,
                          float* __restrict__ sea, int E) {
    int e = blockIdx.x * 256 + threadIdx.x;
    if (e >= E) return;
    int r = rows[e];
    int pos = base[r] + atomicAdd(&fill[r], 1);
    srow[pos] = r;
    scol[pos] = cols[e];
    sea[pos * 2 + 0] = eattr[(size_t)e * 2 + 0];
    sea[pos * 2 + 1] = eattr[(size_t)e * 2 + 1];
}

__global__ void k_embed(const float* __restrict__ hin, const float* __restrict__ w,
                        const float* __restrict__ b, float* __restrict__ hout, int N) {
    int idx = blockIdx.x * 256 + threadIdx.x;
    if (idx >= N * HID) return;
    int n = idx >> 7, j = idx & 127;
    float s = b[j];
    const float* hr = &hin[n * 6];
#pragma unroll
    for (int k = 0; k < 6; ++k) s += hr[k] * w[k * HID + j];
    hout[idx] = s;
}

// pack weights TRANSPOSED as MFMA A-operand fragments (weights = A, edges = B):
// A[m=n_out within 32-tile][k]: lane owns m=lane&31, k=(lane>>5)*8+j.
// chunk layout: [(kc*4 + t4)*64 + lane]*8 + j. w1a: 17 kc (K=259+bias+pad);
// w2a/c1a: 9 kc (K=128+bias+pad). Split hi/lo planes. Also pack per-lane
// coefficient tables awp/cw2p[l][l5*64 + t4*16+reg] matching the C-row pattern.
__global__ void k_pack_a(const float* __restrict__ ew1, const float* __restrict__ eb1,
                         const float* __restrict__ ew2, const float* __restrict__ eb2,
                         const float* __restrict__ cw1, const float* __restrict__ cb1,
                         const float* __restrict__ aw, const float* __restrict__ cw2,
                         us* __restrict__ w1ah, us* __restrict__ w1al,
                         us* __restrict__ w2ah, us* __restrict__ w2al,
                         us* __restrict__ c1ah, us* __restrict__ c1al,
                         float* __restrict__ awp, float* __restrict__ cw2p) {
    int idx = blockIdx.x * 256 + threadIdx.x;
    const int total = 4 * 35 * 2048;
    if (idx < total) {
        int l = idx / (35 * 2048);
        int off = idx % (35 * 2048);
        int mat, kc, c;
        if (off < 17 * 2048) { mat = 0; kc = off >> 11; c = off & 2047; }
        else if (off < 26 * 2048) { mat = 1; int o2 = off - 17 * 2048; kc = o2 >> 11; c = o2 & 2047; }
        else { mat = 2; int o2 = off - 26 * 2048; kc = o2 >> 11; c = o2 & 2047; }
        int t4 = c >> 9, lane = (c >> 3) & 63, j = c & 7;
        int k = kc * 16 + ((lane >> 5) << 3) + j;
        int n = (t4 << 5) + (lane & 31);
        float f = 0.f;
        if (mat == 0) {
            if (k < 259) f = ew1[(size_t)l * 33152 + k * 128 + n];
            else if (k == 259) f = eb1[l * 128 + n];
        } else if (mat == 1) {
            if (k < 128) f = ew2[(size_t)l * 16384 + k * 128 + n];
            else if (k == 128) f = eb2[l * 128 + n];
        } else {
            if (k < 128) f = cw1[(size_t)l * 16384 + k * 128 + n];
            else if (k == 128) f = cb1[l * 128 + n];
        }
        us hi = bf16hi(f);
        us lo = bf16hi(f - bf16tof(hi));
        int o = ((kc * 4 + t4) * 64 + lane) * 8 + j;
        if (mat == 0) { w1ah[(size_t)l * 34816 + o] = hi; w1al[(size_t)l * 34816 + o] = lo; }
        else if (mat == 1) { w2ah[(size_t)l * 18432 + o] = hi; w2al[(size_t)l * 18432 + o] = lo; }
        else { c1ah[(size_t)l * 18432 + o] = hi; c1al[(size_t)l * 18432 + o] = lo; }
    } else if (idx < total + 1024) {
        int q = idx - total;
        int l = q >> 8;
        int rest = q & 255;
        int tb = rest >> 7, i = rest & 127;
        int half = i >> 6, qq = i & 63;
        int t4 = qq >> 4, reg = qq & 15;
        int n = (t4 << 5) + (reg & 3) + ((reg >> 2) << 3) + (half << 2);
        if (tb == 0) awp[l * 128 + i] = aw[l * 128 + n];
        else         cw2p[l * 128 + i] = cw2[l * 128 + n];
    }
}

__global__ void k_prep_h(const float* __restrict__ h, us* __restrict__ hhi,
                         us* __restrict__ hlo, int N) {
    int idx = blockIdx.x * 256 + threadIdx.x;
    if (idx >= N * HID) return;
    float f = h[idx];
    us hi = bf16hi(f);
    hhi[idx] = hi;
    hlo[idx] = bf16hi(f - bf16tof(hi));
}

// Transposed edge kernel: D[n][e]; weights=A, edges=B. One wave = 32 edges.
// No LDS, no __syncthreads, no aggregation atomics for m (streamed to mbuf).
__global__ __launch_bounds__(256, 2) void k_edge_mfma(
    const us* __restrict__ hhi, const us* __restrict__ hlo,
    const float* __restrict__ x,
    const int* __restrict__ srow, const int* __restrict__ scol,
    const float* __restrict__ sea,
    const us* __restrict__ w1ah, const us* __restrict__ w1al,
    const us* __restrict__ w2ah, const us* __restrict__ w2al,
    const us* __restrict__ c1ah, const us* __restrict__ c1al,
    const float* __restrict__ awp, const float* __restrict__ cw2p,
    const float* __restrict__ ab,
    float* __restrict__ mbuf, float* __restrict__ aggx, int E)
{
    const int t = threadIdx.x;
    const int wv = t >> 6, lane = t & 63;
    const int l5 = lane >> 5, ll = lane & 31;
    const int e = (blockIdx.x * 4 + wv) * 32 + ll;
    const int ec = e < E ? e : E - 1;

    const int rN = srow[ec], cN = scol[ec];
    float dx = x[rN * 3 + 0] - x[cN * 3 + 0];
    float dy = x[rN * 3 + 1] - x[cN * 3 + 1];
    float dz = x[rN * 3 + 2] - x[cN * 3 + 2];
    float rad = dx * dx + dy * dy + dz * dz;
    float ea0 = sea[(size_t)ec * 2 + 0];
    float ea1 = sea[(size_t)ec * 2 + 1];

    // virtual B chunk for GEMM1 tail: k = [radial, ea0, ea1, 1, 0...] (l5==0 half)
    bf16x8 bvh, bvl;
    {
        float vv[8] = {0.f, 0.f, 0.f, 0.f, 0.f, 0.f, 0.f, 0.f};
        if (l5 == 0) { vv[0] = rad; vv[1] = ea0; vv[2] = ea1; vv[3] = 1.0f; }
        split8(vv, bvh, bvl);
        if (l5 != 0) { bvh = (bf16x8)(short)0; bvl = (bf16x8)(short)0; }
    }
    // bias-only B chunk (B=1 at k=0 of l5==0)
    bf16x8 bone = (bf16x8)(short)0;
    if (l5 == 0) bone[0] = (short)0x3F80;

    // ---- GEMM1: A1[n1 4-tiles][e] over K=256 gathered h + virtual chunk ----
    f32x16 A1[4];
#pragma unroll
    for (int i = 0; i < 4; ++i)
#pragma unroll
        for (int j = 0; j < 16; ++j) A1[i][j] = 0.f;
#pragma unroll
    for (int kc = 0; kc < 16; ++kc) {
        int node = (kc < 8) ? rN : cN;
        int ko = ((kc & 7) << 4) + (l5 << 3);
        bf16x8 bh = *(const bf16x8*)(hhi + (size_t)node * HID + ko);
        bf16x8 bl = *(const bf16x8*)(hlo + (size_t)node * HID + ko);
#pragma unroll
        for (int t4 = 0; t4 < 4; ++t4) {
            const us* ap = w1ah + ((kc * 4 + t4) * 64 + lane) * 8;
            const us* al = w1al + ((kc * 4 + t4) * 64 + lane) * 8;
            A1[t4] = mfma3(*(const bf16x8*)ap, *(const bf16x8*)al, bh, bl, A1[t4]);
        }
    }
#pragma unroll
    for (int t4 = 0; t4 < 4; ++t4) {
        const us* ap = w1ah + ((16 * 4 + t4) * 64 + lane) * 8;
        const us* al = w1al + ((16 * 4 + t4) * 64 + lane) * 8;
        A1[t4] = mfma3(*(const bf16x8*)ap, *(const bf16x8*)al, bvh, bvl, A1[t4]);
    }

    // ---- GEMM2: A2 = silu(A1-full) @ w2 (t1 assembled via xor-32 exchange) ----
    f32x16 A2[4];
#pragma unroll
    for (int i = 0; i < 4; ++i)
#pragma unroll
        for (int j = 0; j < 16; ++j) A2[i][j] = 0.f;
#pragma unroll
    for (int kc = 0; kc < 8; ++kc) {
        const int tile = kc >> 1, qb = (kc & 1) << 3;
        float v[8];
#pragma unroll
        for (int rr = 0; rr < 4; ++rr) {
            float so = l5 ? A1[tile][rr + qb] : A1[tile][rr + 4 + qb];
            float keep = l5 ? A1[tile][rr + 4 + qb] : A1[tile][rr + qb];
            float rec = __shfl_xor(so, 32);
            v[rr] = silu_f(l5 ? rec : keep);
            v[rr + 4] = silu_f(l5 ? keep : rec);
        }
        bf16x8 bh, bl;
        split8(v, bh, bl);
#pragma unroll
        for (int t4 = 0; t4 < 4; ++t4) {
            const us* ap = w2ah + ((kc * 4 + t4) * 64 + lane) * 8;
            const us* al = w2al + ((kc * 4 + t4) * 64 + lane) * 8;
            A2[t4] = mfma3(*(const bf16x8*)ap, *(const bf16x8*)al, bh, bl, A2[t4]);
        }
    }
#pragma unroll
    for (int t4 = 0; t4 < 4; ++t4) {   // bias chunk kc=8
        const us* ap = w2ah + ((8 * 4 + t4) * 64 + lane) * 8;
        const us* al = w2al + ((8 * 4 + t4) * 64 + lane) * 8;
        A2[t4] = mfma2(*(const bf16x8*)ap, *(const bf16x8*)al, bone, A2[t4]);
    }

    // ---- attention gate: p = sum_n aw[n]*silu(t2[n][e]) ----
    float att;
    {
        float p = 0.f;
        const float4* aw4 = (const float4*)(awp + (l5 << 6));
#pragma unroll
        for (int t4 = 0; t4 < 4; ++t4)
#pragma unroll
            for (int rq = 0; rq < 4; ++rq) {
                float4 cv = aw4[t4 * 4 + rq];
                p += cv.x * silu_f(A2[t4][rq * 4 + 0]);
                p += cv.y * silu_f(A2[t4][rq * 4 + 1]);
                p += cv.z * silu_f(A2[t4][rq * 4 + 2]);
                p += cv.w * silu_f(A2[t4][rq * 4 + 3]);
            }
        p += __shfl_xor(p, 32);
        att = sigmoid_f(p + ab[0]);
    }

    // ---- GEMM3 (+ stream m to mbuf): m = silu(t2)*att; A3 = m @ cw1 ----
    f32x16 A3[4];
#pragma unroll
    for (int i = 0; i < 4; ++i)
#pragma unroll
        for (int j = 0; j < 16; ++j) A3[i][j] = 0.f;
    float* mrow = mbuf + (size_t)ec * HID;
#pragma unroll
    for (int kc = 0; kc < 8; ++kc) {
        const int tile = kc >> 1, qb = (kc & 1) << 3;
        float v[8];
#pragma unroll
        for (int rr = 0; rr < 4; ++rr) {
            float so = l5 ? A2[tile][rr + qb] : A2[tile][rr + 4 + qb];
            float keep = l5 ? A2[tile][rr + 4 + qb] : A2[tile][rr + qb];
            float rec = __shfl_xor(so, 32);
            v[rr] = silu_f(l5 ? rec : keep) * att;
            v[rr + 4] = silu_f(l5 ? keep : rec) * att;
        }
        if (e < E) {
            *(float4*)(mrow + (kc << 4) + (l5 << 3)) = make_float4(v[0], v[1], v[2], v[3]);
            *(float4*)(mrow + (kc << 4) + (l5 << 3) + 4) = make_float4(v[4], v[5], v[6], v[7]);
        }
        bf16x8 bh, bl;
        split8(v, bh, bl);
#pragma unroll
        for (int t4 = 0; t4 < 4; ++t4) {
            const us* ap = c1ah + ((kc * 4 + t4) * 64 + lane) * 8;
            const us* al = c1al + ((kc * 4 + t4) * 64 + lane) * 8;
            A3[t4] = mfma3(*(const bf16x8*)ap, *(const bf16x8*)al, bh, bl, A3[t4]);
        }
    }
#pragma unroll
    for (int t4 = 0; t4 < 4; ++t4) {   // bias chunk kc=8
        const us* ap = c1ah + ((8 * 4 + t4) * 64 + lane) * 8;
        const us* al = c1al + ((8 * 4 + t4) * 64 + lane) * 8;
        A3[t4] = mfma2(*(const bf16x8*)ap, *(const bf16x8*)al, bone, A3[t4]);
    }

    // ---- wc = sum_n cw2[n]*silu(u[n][e]); aggx atomics ----
    {
        float wc = 0.f;
        const float4* cw4 = (const float4*)(cw2p + (l5 << 6));
#pragma unroll
        for (int t4 = 0; t4 < 4; ++t4)
#pragma unroll
            for (int rq = 0; rq < 4; ++rq) {
                float4 cv = cw4[t4 * 4 + rq];
                wc += cv.x * silu_f(A3[t4][rq * 4 + 0]);
                wc += cv.y * silu_f(A3[t4][rq * 4 + 1]);
                wc += cv.z * silu_f(A3[t4][rq * 4 + 2]);
                wc += cv.w * silu_f(A3[t4][rq * 4 + 3]);
            }
        wc += __shfl_xor(wc, 32);
        if (l5 == 0 && e < E) {
            atomicAdd(&aggx[rN * 3 + 0], dx * wc);
            atomicAdd(&aggx[rN * 3 + 1], dy * wc);
            atomicAdd(&aggx[rN * 3 + 2], dz * wc);
        }
    }
}

// 64 nodes per block; agg_h computed in-kernel via CSR sum over mbuf
__global__ __launch_bounds__(256, 2) void k_node(
    float* __restrict__ h, const float* __restrict__ mbuf,
    const int* __restrict__ basei,
    const float* __restrict__ aggx, const int* __restrict__ cnti,
    float* __restrict__ x, float* __restrict__ vel,
    const float* __restrict__ vw1, const float* __restrict__ vb1,
    const float* __restrict__ vw2, const float* __restrict__ vb2,
    const float* __restrict__ nw1, const float* __restrict__ nb1,
    const float* __restrict__ nw2, const float* __restrict__ nb2,
    int N)
{
    __shared__ __align__(16) float BH[64][132];
    __shared__ __align__(16) float BG[64][132];
    const int t = threadIdx.x;
    const int tx = t & 15, ty = t >> 4;
    const int n0 = blockIdx.x * 64;

    for (int idx = t; idx < 64 * 32; idx += 256) {
        int r = idx >> 5, c4 = idx & 31;
        int n = n0 + r;
        float4 v0 = make_float4(0.f, 0.f, 0.f, 0.f);
        if (n < N) v0 = *(const float4*)&h[(size_t)n * HID + c4 * 4];
        *(float4*)&BH[r][c4 * 4] = v0;
    }
    // CSR segment-sum of m into BG: thread (ty,tx) covers nodes ty*4..+3, cols tx*8..+7
#pragma unroll
    for (int i = 0; i < 4; ++i) {
        int n = n0 + ty * 4 + i;
        float4 s0 = make_float4(0.f, 0.f, 0.f, 0.f), s1 = s0;
        if (n < N) {
            int eb = basei[n], ee = eb + cnti[n];
            for (int ed = eb; ed < ee; ++ed) {
                const float* mr = mbuf + (size_t)ed * HID + tx * 8;
                float4 a = *(const float4*)mr;
                float4 b = *(const float4*)(mr + 4);
                s0.x += a.x; s0.y += a.y; s0.z += a.z; s0.w += a.w;
                s1.x += b.x; s1.y += b.y; s1.z += b.z; s1.w += b.w;
            }
        }
        *(float4*)&BG[ty * 4 + i][tx * 8] = s0;
        *(float4*)&BG[ty * 4 + i][tx * 8 + 4] = s1;
    }
    __syncthreads();

    {
        float acc[4][8];
#pragma unroll
        for (int i = 0; i < 4; ++i)
#pragma unroll
            for (int j = 0; j < 8; ++j) acc[i][j] = 0.f;
        const float* wp = &vw1[tx * 8];
#pragma unroll 4
        for (int k = 0; k < HID; ++k) {
            float4 w0 = *(const float4*)&wp[k * HID];
            float4 w1v = *(const float4*)&wp[k * HID + 4];
            float wvv[8] = {w0.x, w0.y, w0.z, w0.w, w1v.x, w1v.y, w1v.z, w1v.w};
            float av[4];
#pragma unroll
            for (int i = 0; i < 4; ++i) av[i] = BH[ty * 4 + i][k];
#pragma unroll
            for (int i = 0; i < 4; ++i)
#pragma unroll
                for (int j = 0; j < 8; ++j) acc[i][j] += av[i] * wvv[j];
        }
        float bb[8], w2v[8];
#pragma unroll
        for (int j = 0; j < 8; ++j) { bb[j] = vb1[tx * 8 + j]; w2v[j] = vw2[tx * 8 + j]; }
        float vb20 = vb2[0];
#pragma unroll
        for (int i = 0; i < 4; ++i) {
            float p = 0.f;
#pragma unroll
            for (int j = 0; j < 8; ++j) p += silu_f(acc[i][j] + bb[j]) * w2v[j];
            p += __shfl_xor(p, 1);
            p += __shfl_xor(p, 2);
            p += __shfl_xor(p, 4);
            p += __shfl_xor(p, 8);
            float vs = p + vb20;
            if (tx == 0) {
                int n = n0 + ty * 4 + i;
                if (n < N) {
                    float cc = fmaxf((float)cnti[n], 1.0f);
#pragma unroll
                    for (int d = 0; d < 3; ++d) {
                        float vn = vs * vel[n * 3 + d];
                        float xn = x[n * 3 + d] + aggx[n * 3 + d] / cc + vn;
                        vel[n * 3 + d] = vn;
                        x[n * 3 + d] = xn;
                    }
                }
            }
        }
    }

    float acc2[4][8];
#pragma unroll
    for (int i = 0; i < 4; ++i)
#pragma unroll
        for (int j = 0; j < 8; ++j) acc2[i][j] = 0.f;
    {
        const float* wp = &nw1[tx * 8];
#pragma unroll 4
        for (int k = 0; k < HID; ++k) {
            float4 w0 = *(const float4*)&wp[k * HID];
            float4 w1v = *(const float4*)&wp[k * HID + 4];
            float wvv[8] = {w0.x, w0.y, w0.z, w0.w, w1v.x, w1v.y, w1v.z, w1v.w};
            float av[4];
#pragma unroll
            for (int i = 0; i < 4; ++i) av[i] = BH[ty * 4 + i][k];
#pragma unroll
            for (int i = 0; i < 4; ++i)
#pragma unroll
                for (int j = 0; j < 8; ++j) acc2[i][j] += av[i] * wvv[j];
        }
        const float* wp2 = &nw1[128 * HID + tx * 8];
#pragma unroll 4
        for (int k = 0; k < HID; ++k) {
            float4 w0 = *(const float4*)&wp2[k * HID];
            float4 w1v = *(const float4*)&wp2[k * HID + 4];
            float wvv[8] = {w0.x, w0.y, w0.z, w0.w, w1v.x, w1v.y, w1v.z, w1v.w};
            float av[4];
#pragma unroll
            for (int i = 0; i < 4; ++i) av[i] = BG[ty * 4 + i][k];
#pragma unroll
            for (int i = 0; i < 4; ++i)
#pragma unroll
                for (int j = 0; j < 8; ++j) acc2[i][j] += av[i] * wvv[j];
        }
    }
    __syncthreads();
    {
        float bb[8];
#pragma unroll
        for (int j = 0; j < 8; ++j) bb[j] = nb1[tx * 8 + j];
#pragma unroll
        for (int i = 0; i < 4; ++i)
#pragma unroll
            for (int j = 0; j < 8; ++j)
                BH[ty * 4 + i][tx * 8 + j] = silu_f(acc2[i][j] + bb[j]);
    }
    __syncthreads();
    float acc3[4][8];
#pragma unroll
    for (int i = 0; i < 4; ++i)
#pragma unroll
        for (int j = 0; j < 8; ++j) acc3[i][j] = 0.f;
    {
        const float* wp = &nw2[tx * 8];
#pragma unroll 4
        for (int k = 0; k < HID; ++k) {
            float4 w0 = *(const float4*)&wp[k * HID];
            float4 w1v = *(const float4*)&wp[k * HID + 4];
            float wvv[8] = {w0.x, w0.y, w0.z, w0.w, w1v.x, w1v.y, w1v.z, w1v.w};
            float av[4];
#pragma unroll
            for (int i = 0; i < 4; ++i) av[i] = BH[ty * 4 + i][k];
#pragma unroll
            for (int i = 0; i < 4; ++i)
#pragma unroll
                for (int j = 0; j < 8; ++j) acc3[i][j] += av[i] * wvv[j];
        }
    }
    {
        float bb[8];
#pragma unroll
        for (int j = 0; j < 8; ++j) bb[j] = nb2[tx * 8 + j];
#pragma unroll
        for (int i = 0; i < 4; ++i) {
            int n = n0 + ty * 4 + i;
            if (n < N) {
#pragma unroll
                for (int j = 0; j < 8; ++j)
                    h[(size_t)n * HID + tx * 8 + j] = acc3[i][j] + bb[j];
            }
        }
    }
}

__global__ void k_proj(const float* __restrict__ h, const float* __restrict__ pw,
                       const float* __restrict__ pb, float* __restrict__ out, int N) {
    int idx = blockIdx.x * 256 + threadIdx.x;
    if (idx >= N * 3) return;
    int n = idx / 3, p = idx % 3;
    float s = pb[p];
    const float* hr = &h[(size_t)n * HID];
#pragma unroll 8
    for (int k = 0; k < HID; ++k) s += hr[k] * pw[k * 3 + p];
    out[idx] = s;
}

extern "C" void kernel_launch(void* const* d_in, const int* in_sizes, int n_in,
                              void* d_out, int out_size, void* d_ws, size_t ws_size,
                              hipStream_t stream)
{
    const float* h_in  = (const float*)d_in[0];
    const float* x_in  = (const float*)d_in[1];
    const float* v_in  = (const float*)d_in[2];
    const float* eattr = (const float*)d_in[3];
    const int*   edges = (const int*)d_in[4];
    const float* emb_w = (const float*)d_in[5];
    const float* emb_b = (const float*)d_in[6];
    const float* ew1   = (const float*)d_in[7];
    const float* eb1   = (const float*)d_in[8];
    const float* ew2   = (const float*)d_in[9];
    const float* eb2   = (const float*)d_in[10];
    const float* aw    = (const float*)d_in[11];
    const float* ab    = (const float*)d_in[12];
    const float* nw1   = (const float*)d_in[13];
    const float* nb1   = (const float*)d_in[14];
    const float* nw2   = (const float*)d_in[15];
    const float* nb2   = (const float*)d_in[16];
    const float* cw1   = (const float*)d_in[17];
    const float* cb1   = (const float*)d_in[18];
    const float* cw2   = (const float*)d_in[19];
    const float* vw1   = (const float*)d_in[20];
    const float* vb1   = (const float*)d_in[21];
    const float* vw2   = (const float*)d_in[22];
    const float* vb2   = (const float*)d_in[23];
    const float* pw    = (const float*)d_in[24];
    const float* pb    = (const float*)d_in[25];

    const int N = in_sizes[0] / 6;
    const int E = in_sizes[4] / 2;
    const int* rows = edges;
    const int* cols = edges + E;

    float* ws   = (float*)d_ws;
    float* hbuf = ws;  ws += (size_t)N * HID;
    float* aggx = ws;  ws += (size_t)N * 3;
    float* xb   = ws;  ws += (size_t)N * 3;
    float* vb   = ws;  ws += (size_t)N * 3;
    float* sea  = ws;  ws += (size_t)E * 2;
    int* wi = (int*)ws;
    int* cnti = wi;  wi += N;
    int* basei = wi; wi += N;
    int* fill = wi;  wi += N;
    int* srow = wi;  wi += E;
    int* scol = wi;  wi += E;
    us* usp = (us*)wi;
    us* hhi = usp;  usp += (size_t)N * HID;
    us* hlo = usp;  usp += (size_t)N * HID;
    us* w1ah = usp; usp += 4 * 34816;
    us* w1al = usp; usp += 4 * 34816;
    us* w2ah = usp; usp += 4 * 18432;
    us* w2al = usp; usp += 4 * 18432;
    us* c1ah = usp; usp += 4 * 18432;
    us* c1al = usp; usp += 4 * 18432;
    float* fp = (float*)usp;
    float* awp  = fp; fp += 4 * 128;
    float* cw2p = fp; fp += 4 * 128;
    float* mbuf = fp; fp += (size_t)E * HID;   // 164 MB
    float* outp = (float*)d_out;

    hipMemcpyAsync(xb, x_in, (size_t)N * 3 * sizeof(float), hipMemcpyDeviceToDevice, stream);
    hipMemcpyAsync(vb, v_in, (size_t)N * 3 * sizeof(float), hipMemcpyDeviceToDevice, stream);
    hipMemsetAsync(cnti, 0, N * sizeof(int), stream);
    hipMemsetAsync(fill, 0, N * sizeof(int), stream);
    k_cnt<<<(E + 255) / 256, 256, 0, stream>>>(rows, cnti, E);
    k_scan<<<1, 256, 0, stream>>>(cnti, basei, N);
    k_scatter<<<(E + 255) / 256, 256, 0, stream>>>(rows, cols, eattr, basei, fill,
                                                   srow, scol, sea, E);
    k_pack_a<<<(4 * 35 * 2048 + 1024 + 255) / 256, 256, 0, stream>>>(
        ew1, eb1, ew2, eb2, cw1, cb1, aw, cw2,
        w1ah, w1al, w2ah, w2al, c1ah, c1al, awp, cw2p);
    k_embed<<<(N * HID + 255) / 256, 256, 0, stream>>>(h_in, emb_w, emb_b, hbuf, N);

    for (int l = 0; l < 4; ++l) {
        k_prep_h<<<(N * HID + 255) / 256, 256, 0, stream>>>(hbuf, hhi, hlo, N);
        hipMemsetAsync(aggx, 0, (size_t)N * 3 * sizeof(float), stream);
        k_edge_mfma<<<(E + 127) / 128, 256, 0, stream>>>(
            hhi, hlo, xb, srow, scol, sea,
            w1ah + (size_t)l * 34816, w1al + (size_t)l * 34816,
            w2ah + (size_t)l * 18432, w2al + (size_t)l * 18432,
            c1ah + (size_t)l * 18432, c1al + (size_t)l * 18432,
            awp + l * 128, cw2p + l * 128, ab + l,
            mbuf, aggx, E);
        k_node<<<(N + 63) / 64, 256, 0, stream>>>(
            hbuf, mbuf, basei, aggx, cnti, xb, vb,
            vw1 + (size_t)l * HID * HID, vb1 + l * HID, vw2 + l * HID, vb2 + l,
            nw1 + (size_t)l * 2 * HID * HID, nb1 + l * HID,
            nw2 + (size_t)l * HID * HID, nb2 + l * HID, N);
    }
    k_proj<<<(N * 3 + 255) / 256, 256, 0, stream>>>(hbuf, pw, pb, outp, N);
    hipMemcpyAsync(outp + (size_t)N * 3, xb, (size_t)N * 3 * sizeof(float), hipMemcpyDeviceToDevice, stream);
    hipMemcpyAsync(outp + (size_t)N * 6, vb, (size_t)N * 3 * sizeof(float), hipMemcpyDeviceToDevice, stream);
}